// Round 11
// baseline (82.440 us; speedup 1.0000x reference)
//
#include <hip/hip_runtime.h>
#include <hip/hip_bf16.h>

typedef __attribute__((ext_vector_type(8))) short bf16x8;   // 8 bf16 = 4 VGPRs
typedef __attribute__((ext_vector_type(4))) float f32x4;

__device__ __forceinline__ short f2bf(float v) {
    unsigned u = __builtin_bit_cast(unsigned, v);
    u += 0x7fffu + ((u >> 16) & 1u);          // round-to-nearest-even
    return (short)(u >> 16);
}
__device__ __forceinline__ float relu(float v) { return v > 0.f ? v : 0.f; }

// Slab geometry (v7-verified): [64 ch][2 rows][64 w], +4-float row pad.
#define ROWP 68                 // floats per (ch,row) row
#define CHP  136                // floats per ch (2 rows)

// ---------------- prep: build bf16 W-fragments into d_ws ----------------
// Slot (mt=j*8+ot, kt, lane): lane l holds W[o = ot*16 + (l&15)][c = kt*32 + (l>>4)*8 + e].
// Same (group,elem)->k map as the X operand so the HW k-permutation cancels
// (numerically verified R1-R10).
__global__ __launch_bounds__(64)
void prep_wfrag(const float* __restrict__ w, bf16x8* __restrict__ wf) {
    const int mt   = blockIdx.x >> 2;       // 0..39
    const int kt   = blockIdx.x & 3;        // 0..3
    const int lane = threadIdx.x;           // 0..63
    const int j  = mt >> 3;
    const int ot = mt & 7;
    const int o  = ot * 16 + (lane & 15);
    const int c0 = kt * 32 + (lane >> 4) * 8;
    const float* wp = w + ((size_t)o * 128 + c0) * 5 + j;
    bf16x8 f;
    #pragma unroll
    for (int e = 0; e < 8; ++e) f[e] = f2bf(wp[e * 5]);
    wf[(size_t)(mt * 4 + kt) * 64 + lane] = f;
}

// ---------------- main: one block per (n, row-pair) ----------------
// Byte-identical structure to v7 (champion, 76 µs) EXCEPT: compute is per-oi
// with immediate slab write (live acc = 8 VGPR, not 32) and launch_bounds
// (512,8) forces VGPR<=64 so 4 blocks/CU co-reside (LDS 34KB also allows 4).
// Goal: double resident blocks -> store-drain duty cycle up -> write BW up.
__global__ __launch_bounds__(512, 8)
void sconv_v11(const float* __restrict__ x, const bf16x8* __restrict__ wf,
               float* __restrict__ out) {
    __shared__ float lds[64 * CHP];         // ~34 KiB

    const int bid = blockIdx.x;
    const int hp = bid & 31;                // row pair index
    const int n  = bid >> 5;
    const int h0 = hp * 2;

    const int t    = threadIdx.x;
    const int wave = t >> 6;
    const int lane = t & 63;
    const int mh   = wave >> 2;             // channel half owned by this wave
    const int pt   = wave & 3;              // 16-wide position tile
    const int l15  = lane & 15;
    const int lg   = lane >> 4;
    const int pos  = pt * 16 + l15;         // gather position (A row map)

    // ---- gather X fragments for both rows, kept in regs (v7-identical) ----
    const float* xb = x + (size_t)n * 128 * 4096 + (size_t)(h0 * 64 + pos);
    bf16x8 xf[2][4];
    #pragma unroll
    for (int r = 0; r < 2; ++r) {
        #pragma unroll
        for (int kt = 0; kt < 4; ++kt) {
            const float* xp = xb + (size_t)r * 64
                            + (size_t)(kt * 32 + lg * 8) * 4096;
            bf16x8 f;
            #pragma unroll
            for (int e = 0; e < 8; ++e) f[e] = f2bf(xp[(size_t)e * 4096]);
            xf[r][kt] = f;
        }
    }

    const int wq  = pt * 4 + lg;            // quad this lane's acc covers
    const int wp0 = pt * 16 + lg * 4;       // first position of that quad

    #pragma unroll
    for (int j = 0; j < 5; ++j) {
        #pragma unroll
        for (int p = 0; p < 2; ++p) {
            // never-written edge column zero-fill for w-shifted taps
            if (j == 1 && t < 128)
                lds[(t >> 1) * CHP + (t & 1) * ROWP + 0] = 0.f;
            if (j == 3 && t < 128)
                lds[(t >> 1) * CHP + (t & 1) * ROWP + 63] = 0.f;

            // ---- compute channel half p (waves mh==p), per-oi immediate ----
            if (mh == p) {
                #pragma unroll
                for (int oi = 0; oi < 4; ++oi) {
                    const int ot = p * 4 + oi;
                    const int cl = oi * 16 + l15;   // ch within this half
                    const bf16x8* wfp =
                        wf + (size_t)((j * 8 + ot) * 4) * 64 + lane;
                    f32x4 a0 = {0.f, 0.f, 0.f, 0.f};
                    f32x4 a1 = {0.f, 0.f, 0.f, 0.f};
                    #pragma unroll
                    for (int kt = 0; kt < 4; ++kt) {
                        const bf16x8 b = wfp[(size_t)kt * 64];
                        a0 = __builtin_amdgcn_mfma_f32_16x16x32_bf16(
                            xf[0][kt], b, a0, 0, 0, 0);
                        a1 = __builtin_amdgcn_mfma_f32_16x16x32_bf16(
                            xf[1][kt], b, a1, 0, 0, 0);
                    }
                    float* const row0 = &lds[cl * CHP];
                    if (j == 0 || j == 2 || j == 4) {
                        f32x4 v0, v1;
                        #pragma unroll
                        for (int q = 0; q < 4; ++q) {
                            v0[q] = relu(a0[q]); v1[q] = relu(a1[q]);
                        }
                        *reinterpret_cast<f32x4*>(row0 + wq * 4)        = v0;
                        *reinterpret_cast<f32x4*>(row0 + ROWP + wq * 4) = v1;
                    } else {
                        const int d = (j == 1) ? 1 : -1;
                        #pragma unroll
                        for (int q = 0; q < 4; ++q) {
                            const int ws = wp0 + q + d;
                            if ((unsigned)ws < 64u) {
                                row0[ws]        = relu(a0[q]);
                                row0[ROWP + ws] = relu(a1[q]);
                            }
                        }
                    }
                }
            }
            __syncthreads();

            // ---- drain: one instr = 512B contiguous (v7-identical) ----
            #pragma unroll
            for (int i = 0; i < 4; ++i) {
                const int g  = i * 512 + t;
                const int cl = g >> 5;          // 0..63
                const int hr = (g >> 4) & 1;    // row within pair
                const int q  = g & 15;          // quad within row
                f32x4 v = *reinterpret_cast<const f32x4*>(
                    &lds[cl * CHP + hr * ROWP + q * 4]);
                const int hh = h0 + hr;
                const int hs = (j == 0) ? ((hh + 1) & 63)
                             : (j == 4) ? ((hh + 63) & 63) : hh;
                if ((j == 0 && hh == 63) || (j == 4 && hh == 0))
                    v = f32x4{0.f, 0.f, 0.f, 0.f};
                __builtin_nontemporal_store(
                    v, reinterpret_cast<f32x4*>(
                           out + (((size_t)n * 640 + j * 128 + p * 64 + cl) * 64
                                  + hs) * 64 + q * 4));
            }
            if (j < 4 || p < 1) __syncthreads();
        }
    }
}

// ---------------- fallback (R1 kernel) if workspace is too small ----------------
__global__ __launch_bounds__(512, 2)
void sconv_mfma(const float* __restrict__ x, const float* __restrict__ w,
                float* __restrict__ out) {
    __shared__ bf16x8 wfrag[8][4][64];
    const int bid = blockIdx.x;
    const int j   = bid % 5;
    const int hp  = (bid / 5) % 32;
    const int n   = bid / 160;
    const int t = threadIdx.x;
    for (int s = t; s < 2048; s += 512) {
        const int lane = s & 63;
        const int rest = s >> 6;
        const int mt   = rest >> 2;
        const int kt   = rest & 3;
        const int o    = mt * 16 + (lane & 15);
        const int c0   = kt * 32 + (lane >> 4) * 8;
        const float* wp = w + ((size_t)o * 128 + c0) * 5 + j;
        bf16x8 f;
        #pragma unroll
        for (int e = 0; e < 8; ++e) f[e] = f2bf(wp[e * 5]);
        wfrag[mt][kt][lane] = f;
    }
    __syncthreads();
    const int wave = t >> 6;
    const int lane = t & 63;
    const int l15  = lane & 15;
    const int lg   = lane >> 4;
    const int h    = hp * 2 + (wave >> 2);
    const int wcol = (wave & 3) * 16 + l15;
    const int dy[5] = {-1, 0, 0, 0, 1};
    const int dx[5] = { 0,-1, 0, 1, 0};
    const int hi = h + dy[j];
    const int wi = wcol + dx[j];
    const bool valid = ((unsigned)hi < 64u) && ((unsigned)wi < 64u);
    const int hic = hi < 0 ? 0 : (hi > 63 ? 63 : hi);
    const int wic = wi < 0 ? 0 : (wi > 63 ? 63 : wi);
    const float* xb = x + (size_t)n * 128 * 4096 + (size_t)(hic * 64 + wic);
    bf16x8 xf[4];
    #pragma unroll
    for (int kt = 0; kt < 4; ++kt) {
        const int c0 = kt * 32 + lg * 8;
        const float* xp = xb + (size_t)c0 * 4096;
        bf16x8 f;
        #pragma unroll
        for (int e = 0; e < 8; ++e) {
            float v = xp[(size_t)e * 4096];
            f[e] = f2bf(valid ? v : 0.0f);
        }
        xf[kt] = f;
    }
    f32x4 acc[8];
    #pragma unroll
    for (int mt = 0; mt < 8; ++mt) acc[mt] = f32x4{0.f, 0.f, 0.f, 0.f};
    #pragma unroll
    for (int kt = 0; kt < 4; ++kt)
        #pragma unroll
        for (int mt = 0; mt < 8; ++mt)
            acc[mt] = __builtin_amdgcn_mfma_f32_16x16x32_bf16(
                wfrag[mt][kt][lane], xf[kt], acc[mt], 0, 0, 0);
    float* ob = out + ((size_t)n * 640 + (size_t)j * 128) * 4096
                    + (size_t)(h * 64 + wcol);
    #pragma unroll
    for (int mt = 0; mt < 8; ++mt) {
        const int ch = mt * 16 + lg * 4;
        #pragma unroll
        for (int r = 0; r < 4; ++r) {
            float v = acc[mt][r];
            ob[(size_t)(ch + r) * 4096] = v > 0.f ? v : 0.f;
        }
    }
}

extern "C" void kernel_launch(void* const* d_in, const int* in_sizes, int n_in,
                              void* d_out, int out_size, void* d_ws, size_t ws_size,
                              hipStream_t stream) {
    const float* x = (const float*)d_in[0];   // [32,128,64,64] f32
    const float* w = (const float*)d_in[1];   // [128,128,5] f32
    float* out = (float*)d_out;               // [32,640,64,64] f32

    const size_t wf_bytes = (size_t)40 * 4 * 64 * sizeof(bf16x8);  // 160 KiB
    if (ws_size >= wf_bytes) {
        bf16x8* wf = (bf16x8*)d_ws;
        hipLaunchKernelGGL(prep_wfrag, dim3(160), dim3(64), 0, stream, w, wf);
        hipLaunchKernelGGL(sconv_v11, dim3(32 * 32), dim3(512), 0, stream,
                           x, wf, out);
    } else {
        hipLaunchKernelGGL(sconv_mfma, dim3(32 * 32 * 5), dim3(512), 0, stream,
                           x, w, out);
    }
}

// Round 13
// 76.183 us; speedup vs baseline: 1.0821x; 1.0821x over previous
//
#include <hip/hip_runtime.h>
#include <hip/hip_bf16.h>

typedef __attribute__((ext_vector_type(8))) short bf16x8;   // 8 bf16 = 4 VGPRs
typedef __attribute__((ext_vector_type(4))) float f32x4;

__device__ __forceinline__ short f2bf(float v) {
    unsigned u = __builtin_bit_cast(unsigned, v);
    u += 0x7fffu + ((u >> 16) & 1u);          // round-to-nearest-even
    return (short)(u >> 16);
}
__device__ __forceinline__ float relu(float v) { return v > 0.f ? v : 0.f; }

// LDS slab geometry: [64 ch][2 rows][64 w] with +4-float row pad for bank spread.
#define ROWP 68                 // floats per (ch,row) row
#define CHP  136                // floats per ch (2 rows)

// ---------------- prep: build bf16 W-fragments into d_ws ----------------
// Slot (mt=j*8+ot, kt, lane): lane l holds W[o = ot*16 + (l&15)][c = kt*32 + (l>>4)*8 + e].
// Same (group,elem)->k map as the X operand so the HW k-permutation cancels
// (numerically verified R1-R11).
__global__ __launch_bounds__(64)
void prep_wfrag(const float* __restrict__ w, bf16x8* __restrict__ wf) {
    const int mt   = blockIdx.x >> 2;       // 0..39
    const int kt   = blockIdx.x & 3;        // 0..3
    const int lane = threadIdx.x;           // 0..63
    const int j  = mt >> 3;
    const int ot = mt & 7;
    const int o  = ot * 16 + (lane & 15);
    const int c0 = kt * 32 + (lane >> 4) * 8;
    const float* wp = w + ((size_t)o * 128 + c0) * 5 + j;
    bf16x8 f;
    #pragma unroll
    for (int e = 0; e < 8; ++e) f[e] = f2bf(wp[e * 5]);
    wf[(size_t)(mt * 4 + kt) * 64 + lane] = f;
}

// ---------------- main: one block per (n, row-pair) — FINAL (v7 champion) ----------------
// Unshifted 1x1 GEMM per tap, shift folded into the store side. Per tap, two
// mh-phases drain a [64ch][2row][64w] padded slab; readback lane map
// (2ch x 2row x 16quad) makes each NT dwordx4 instruction cover 2x 512B
// contiguous chunks. w-shifts (j=1/3) folded into slab write with edge-column
// zero-fill; h-shifts (j=0/4) folded into store row with wrap-row zero.
__global__ __launch_bounds__(512, 4)
void sconv_v7(const float* __restrict__ x, const bf16x8* __restrict__ wf,
              float* __restrict__ out) {
    __shared__ float lds[64 * CHP];         // ~34 KiB

    const int bid = blockIdx.x;
    const int hp = bid & 31;                // row pair index
    const int n  = bid >> 5;
    const int h0 = hp * 2;

    const int t    = threadIdx.x;
    const int wave = t >> 6;
    const int lane = t & 63;
    const int mh   = wave >> 2;             // channel half (also phase owner)
    const int pt   = wave & 3;              // 16-wide position tile
    const int l15  = lane & 15;
    const int lg   = lane >> 4;
    const int pos  = pt * 16 + l15;         // gather position (A row map)

    // ---- gather X fragments for both rows, kept in regs ----
    const float* xb = x + (size_t)n * 128 * 4096 + (size_t)(h0 * 64 + pos);
    bf16x8 xf[2][4];
    #pragma unroll
    for (int r = 0; r < 2; ++r) {
        #pragma unroll
        for (int kt = 0; kt < 4; ++kt) {
            const float* xp = xb + (size_t)r * 64
                            + (size_t)(kt * 32 + lg * 8) * 4096;
            bf16x8 f;
            #pragma unroll
            for (int e = 0; e < 8; ++e) f[e] = f2bf(xp[(size_t)e * 4096]);
            xf[r][kt] = f;
        }
    }

    const int wq  = pt * 4 + lg;            // quad this lane's acc covers
    const int wp0 = pt * 16 + lg * 4;       // first position of that quad

    #pragma unroll
    for (int j = 0; j < 5; ++j) {
        // ---- compute: wf loaded once, used for both rows ----
        f32x4 acc[4][2];
        #pragma unroll
        for (int oi = 0; oi < 4; ++oi) {
            const int ot = mh * 4 + oi;
            const bf16x8* wfp = wf + (size_t)((j * 8 + ot) * 4) * 64 + lane;
            acc[oi][0] = f32x4{0.f, 0.f, 0.f, 0.f};
            acc[oi][1] = f32x4{0.f, 0.f, 0.f, 0.f};
            #pragma unroll
            for (int kt = 0; kt < 4; ++kt) {
                const bf16x8 b = wfp[(size_t)kt * 64];
                acc[oi][0] = __builtin_amdgcn_mfma_f32_16x16x32_bf16(
                    xf[0][kt], b, acc[oi][0], 0, 0, 0);
                acc[oi][1] = __builtin_amdgcn_mfma_f32_16x16x32_bf16(
                    xf[1][kt], b, acc[oi][1], 0, 0, 0);
            }
        }

        // ---- two-phase slab drain: p=0 -> ch 0..63, p=1 -> ch 64..127 ----
        #pragma unroll
        for (int p = 0; p < 2; ++p) {
            // edge-column zero-fill for w-shifted taps (disjoint from acc writes)
            if (j == 1 && t < 128) {
                const int cl = t >> 1, r = t & 1;
                lds[cl * CHP + r * ROWP + 0] = 0.f;
            }
            if (j == 3 && t < 128) {
                const int cl = t >> 1, r = t & 1;
                lds[cl * CHP + r * ROWP + 63] = 0.f;
            }
            if (mh == p) {
                #pragma unroll
                for (int oi = 0; oi < 4; ++oi) {
                    const int cl = oi * 16 + l15;   // ch within this half
                    #pragma unroll
                    for (int r = 0; r < 2; ++r) {
                        if (j == 0 || j == 2 || j == 4) {
                            f32x4 v;
                            #pragma unroll
                            for (int q = 0; q < 4; ++q) v[q] = relu(acc[oi][r][q]);
                            *reinterpret_cast<f32x4*>(
                                &lds[cl * CHP + r * ROWP + wq * 4]) = v;
                        } else {
                            #pragma unroll
                            for (int q = 0; q < 4; ++q) {
                                const int ws = wp0 + q + (j == 1 ? 1 : -1);
                                if ((unsigned)ws < 64u)
                                    lds[cl * CHP + r * ROWP + ws]
                                        = relu(acc[oi][r][q]);
                            }
                        }
                    }
                }
            }
            __syncthreads();

            // ---- readback: one instr = 2 ch x 512B-contiguous (2 rows) ----
            #pragma unroll
            for (int i = 0; i < 4; ++i) {
                const int g  = i * 512 + t;
                const int cl = g >> 5;          // 0..63
                const int hr = (g >> 4) & 1;    // row within pair
                const int q  = g & 15;          // quad within row
                f32x4 v = *reinterpret_cast<const f32x4*>(
                    &lds[cl * CHP + hr * ROWP + q * 4]);
                const int h  = h0 + hr;
                const int hs = (j == 0) ? ((h + 1) & 63)
                             : (j == 4) ? ((h + 63) & 63) : h;
                if ((j == 0 && h == 63) || (j == 4 && h == 0))
                    v = f32x4{0.f, 0.f, 0.f, 0.f};
                __builtin_nontemporal_store(
                    v, reinterpret_cast<f32x4*>(
                           out + (((size_t)n * 640 + j * 128 + p * 64 + cl) * 64
                                  + hs) * 64 + q * 4));
            }
            if (j < 4 || p < 1) __syncthreads();
        }
    }
}

// ---------------- fallback (R1 kernel) if workspace is too small ----------------
__global__ __launch_bounds__(512, 2)
void sconv_mfma(const float* __restrict__ x, const float* __restrict__ w,
                float* __restrict__ out) {
    __shared__ bf16x8 wfrag[8][4][64];
    const int bid = blockIdx.x;
    const int j   = bid % 5;
    const int hp  = (bid / 5) % 32;
    const int n   = bid / 160;
    const int t = threadIdx.x;
    for (int s = t; s < 2048; s += 512) {
        const int lane = s & 63;
        const int rest = s >> 6;
        const int mt   = rest >> 2;
        const int kt   = rest & 3;
        const int o    = mt * 16 + (lane & 15);
        const int c0   = kt * 32 + (lane >> 4) * 8;
        const float* wp = w + ((size_t)o * 128 + c0) * 5 + j;
        bf16x8 f;
        #pragma unroll
        for (int e = 0; e < 8; ++e) f[e] = f2bf(wp[e * 5]);
        wfrag[mt][kt][lane] = f;
    }
    __syncthreads();
    const int wave = t >> 6;
    const int lane = t & 63;
    const int l15  = lane & 15;
    const int lg   = lane >> 4;
    const int h    = hp * 2 + (wave >> 2);
    const int wcol = (wave & 3) * 16 + l15;
    const int dy[5] = {-1, 0, 0, 0, 1};
    const int dx[5] = { 0,-1, 0, 1, 0};
    const int hi = h + dy[j];
    const int wi = wcol + dx[j];
    const bool valid = ((unsigned)hi < 64u) && ((unsigned)wi < 64u);
    const int hic = hi < 0 ? 0 : (hi > 63 ? 63 : hi);
    const int wic = wi < 0 ? 0 : (wi > 63 ? 63 : wi);
    const float* xb = x + (size_t)n * 128 * 4096 + (size_t)(hic * 64 + wic);
    bf16x8 xf[4];
    #pragma unroll
    for (int kt = 0; kt < 4; ++kt) {
        const int c0 = kt * 32 + lg * 8;
        const float* xp = xb + (size_t)c0 * 4096;
        bf16x8 f;
        #pragma unroll
        for (int e = 0; e < 8; ++e) {
            float v = xp[(size_t)e * 4096];
            f[e] = f2bf(valid ? v : 0.0f);
        }
        xf[kt] = f;
    }
    f32x4 acc[8];
    #pragma unroll
    for (int mt = 0; mt < 8; ++mt) acc[mt] = f32x4{0.f, 0.f, 0.f, 0.f};
    #pragma unroll
    for (int kt = 0; kt < 4; ++kt)
        #pragma unroll
        for (int mt = 0; mt < 8; ++mt)
            acc[mt] = __builtin_amdgcn_mfma_f32_16x16x32_bf16(
                wfrag[mt][kt][lane], xf[kt], acc[mt], 0, 0, 0);
    float* ob = out + ((size_t)n * 640 + (size_t)j * 128) * 4096
                    + (size_t)(h * 64 + wcol);
    #pragma unroll
    for (int mt = 0; mt < 8; ++mt) {
        const int ch = mt * 16 + lg * 4;
        #pragma unroll
        for (int r = 0; r < 4; ++r) {
            float v = acc[mt][r];
            ob[(size_t)(ch + r) * 4096] = v > 0.f ? v : 0.f;
        }
    }
}

extern "C" void kernel_launch(void* const* d_in, const int* in_sizes, int n_in,
                              void* d_out, int out_size, void* d_ws, size_t ws_size,
                              hipStream_t stream) {
    const float* x = (const float*)d_in[0];   // [32,128,64,64] f32
    const float* w = (const float*)d_in[1];   // [128,128,5] f32
    float* out = (float*)d_out;               // [32,640,64,64] f32

    const size_t wf_bytes = (size_t)40 * 4 * 64 * sizeof(bf16x8);  // 160 KiB
    if (ws_size >= wf_bytes) {
        bf16x8* wf = (bf16x8*)d_ws;
        hipLaunchKernelGGL(prep_wfrag, dim3(160), dim3(64), 0, stream, w, wf);
        hipLaunchKernelGGL(sconv_v7, dim3(32 * 32), dim3(512), 0, stream,
                           x, wf, out);
    } else {
        hipLaunchKernelGGL(sconv_mfma, dim3(32 * 32 * 5), dim3(512), 0, stream,
                           x, w, out);
    }
}